// Round 1
// baseline (6878.545 us; speedup 1.0000x reference)
//
#include <hip/hip_runtime.h>
#include <hip/hip_bf16.h>
#include <math.h>

#define T_TOK 3072
#define HID_D 5120
#define NH 16
#define DN 128
#define DR 64
#define DQK 192
#define DV 128
#define QRANK 1536
#define KVRANK 512

// ---------------- generic fp32 tiled GEMM: C = A @ B ----------------
// A: M x K (lda), B: K x N (ldb), C: M x N (ldc). M % 128 == 0, K % 8 == 0.
// N may be ragged (guarded).
__global__ __launch_bounds__(256) void sgemm_k(
    const float* __restrict__ A, const float* __restrict__ B, float* __restrict__ C,
    int M, int N, int K, int lda, int ldb, int ldc)
{
    __shared__ float As[8][132];
    __shared__ float Bs[8][132];
    const int tid  = threadIdx.x;
    const int row0 = blockIdx.y * 128;
    const int col0 = blockIdx.x * 128;

    float acc[8][8];
#pragma unroll
    for (int i = 0; i < 8; ++i)
#pragma unroll
        for (int j = 0; j < 8; ++j) acc[i][j] = 0.f;

    const int tm = (tid >> 4) << 3;   // compute row base within tile
    const int tn = (tid & 15) << 3;   // compute col base within tile
    const int ar = tid >> 1;          // A load: row within tile
    const int ak = (tid & 1) << 2;    // A load: k offset (float4)
    const int bk = tid >> 5;          // B load: k row
    const int bn = (tid & 31) << 2;   // B load: col offset (float4)

    for (int kt = 0; kt < K; kt += 8) {
        // stage A (transposed into As[k][m])
        const float* ap = A + (size_t)(row0 + ar) * lda + kt + ak;
        float4 av = *(const float4*)ap;
        As[ak + 0][ar] = av.x;
        As[ak + 1][ar] = av.y;
        As[ak + 2][ar] = av.z;
        As[ak + 3][ar] = av.w;
        // stage B
        float4 bv;
        const int bcol = col0 + bn;
        const float* bp = B + (size_t)(kt + bk) * ldb + bcol;
        if (bcol + 3 < N) {
            bv = *(const float4*)bp;
        } else {
            bv.x = (bcol + 0 < N) ? bp[0] : 0.f;
            bv.y = (bcol + 1 < N) ? bp[1] : 0.f;
            bv.z = (bcol + 2 < N) ? bp[2] : 0.f;
            bv.w = (bcol + 3 < N) ? bp[3] : 0.f;
        }
        *(float4*)&Bs[bk][bn] = bv;
        __syncthreads();

#pragma unroll
        for (int k = 0; k < 8; ++k) {
            float af[8], bf[8];
#pragma unroll
            for (int i = 0; i < 8; ++i) af[i] = As[k][tm + i];
#pragma unroll
            for (int j = 0; j < 8; ++j) bf[j] = Bs[k][tn + j];
#pragma unroll
            for (int i = 0; i < 8; ++i)
#pragma unroll
                for (int j = 0; j < 8; ++j)
                    acc[i][j] = fmaf(af[i], bf[j], acc[i][j]);
        }
        __syncthreads();
    }

#pragma unroll
    for (int i = 0; i < 8; ++i) {
        const int r = row0 + tm + i;
        float* cp = C + (size_t)r * ldc + col0 + tn;
#pragma unroll
        for (int j = 0; j < 8; ++j) {
            const int c = col0 + tn + j;
            if (c < N) cp[j] = acc[i][j];
        }
    }
}

// ---------------- RMSNorm (in place), row stride may exceed width ----------------
__global__ __launch_bounds__(256) void rmsnorm_k(float* __restrict__ x,
                                                 const float* __restrict__ w,
                                                 int width, int stride)
{
    const int row = blockIdx.x;
    float* xr = x + (size_t)row * stride;
    float ss = 0.f;
    for (int i = threadIdx.x; i < width; i += 256) {
        float v = xr[i];
        ss += v * v;
    }
    __shared__ float red[256];
    red[threadIdx.x] = ss;
    __syncthreads();
    for (int s = 128; s > 0; s >>= 1) {
        if (threadIdx.x < s) red[threadIdx.x] += red[threadIdx.x + s];
        __syncthreads();
    }
    const float scale = rsqrtf(red[0] / (float)width + 1e-6f);
    for (int i = threadIdx.x; i < width; i += 256) xr[i] = xr[i] * scale * w[i];
}

// ---------------- RoPE on q_pe + llama_4 scaling over full q row ----------------
__global__ void rope_scale_q_k(float* __restrict__ q, const int* __restrict__ positions,
                               const float* __restrict__ scaling,
                               const float* __restrict__ cs_cache)
{
    const int t = blockIdx.x;
    const int pos = positions[t];
    const float* cs = cs_cache + (size_t)pos * DR;  // [cos(32) | sin(32)]
    const float s = scaling[t];
    __shared__ float c_sh[32], s_sh[32];
    if (threadIdx.x < 32) {
        c_sh[threadIdx.x] = cs[threadIdx.x];
        s_sh[threadIdx.x] = cs[32 + threadIdx.x];
    }
    __syncthreads();
    for (int h = 0; h < NH; ++h) {
        float* qr = q + ((size_t)t * NH + h) * DQK;
        const int tid = threadIdx.x;
        if (tid < 128) {
            qr[tid] *= s;
        } else if (tid < 160) {
            const int d = tid - 128;
            const float x1 = qr[128 + d], x2 = qr[160 + d];
            qr[128 + d] = (x1 * c_sh[d] - x2 * s_sh[d]) * s;
            qr[160 + d] = (x2 * c_sh[d] + x1 * s_sh[d]) * s;
        }
    }
}

// ---------------- RoPE on k_pe (from pre-norm latent tail) ----------------
__global__ void rope_k_k(const float* __restrict__ latent, float* __restrict__ kpe,
                         const int* __restrict__ positions,
                         const float* __restrict__ cs_cache)
{
    const int t = blockIdx.x;
    const int d = threadIdx.x;
    if (d >= 32) return;
    const int pos = positions[t];
    const float* cs = cs_cache + (size_t)pos * DR;
    const float c = cs[d], sn = cs[32 + d];
    const float* lr = latent + (size_t)t * (KVRANK + DR) + KVRANK;
    const float x1 = lr[d], x2 = lr[32 + d];
    kpe[(size_t)t * DR + d]      = x1 * c - x2 * sn;
    kpe[(size_t)t * DR + 32 + d] = x2 * c + x1 * sn;
}

// ---------------- causal flash attention (fp32) ----------------
// q: (T, NH, DQK)  kv: (T, NH, DN+DV)  kpe: (T, DR)  attn: (T, NH*DV)
#define BM 32
#define BN 16
__global__ __launch_bounds__(256) void attn_k(
    const float* __restrict__ q, const float* __restrict__ kv,
    const float* __restrict__ kpe, float* __restrict__ attn)
{
    __shared__ float Qs[BM][DQK + 4];
    __shared__ float Ks[BN][DQK + 4];
    __shared__ float Vs[BN][DV + 4];
    __shared__ float Ssh[BM][BN + 1];
    __shared__ float mrow[BM], lrow[BM], arow[BM];

    const int qb = blockIdx.x;
    const int h  = blockIdx.y;
    const int tid = threadIdx.x;
    const int q0 = qb * BM;

    for (int l = tid; l < BM * DQK; l += 256) {
        const int i = l / DQK, d = l % DQK;
        Qs[i][d] = q[((size_t)(q0 + i) * NH + h) * DQK + d];
    }
    if (tid < BM) { mrow[tid] = -3.0e38f; lrow[tid] = 0.f; }

    const int orow = tid >> 3;          // 0..31
    const int oc0  = (tid & 7) << 4;    // 0..112 step 16
    float o[16];
#pragma unroll
    for (int d = 0; d < 16; ++d) o[d] = 0.f;

    const int nkt = (q0 + BM) / BN;     // key tiles covering 0..q0+BM-1
    for (int kt = 0; kt < nkt; ++kt) {
        const int k0 = kt * BN;
        __syncthreads();
        for (int l = tid; l < BN * DQK; l += 256) {
            const int j = l / DQK, d = l % DQK;
            float v;
            if (d < DN) v = kv[((size_t)(k0 + j) * NH + h) * (DN + DV) + d];
            else        v = kpe[(size_t)(k0 + j) * DR + (d - DN)];
            Ks[j][d] = v;
        }
        for (int l = tid; l < BN * DV; l += 256) {
            const int j = l / DV, d = l % DV;
            Vs[j][d] = kv[((size_t)(k0 + j) * NH + h) * (DN + DV) + DN + d];
        }
        __syncthreads();
        {
            const int i0 = (tid >> 4) << 1;
            const int j  = tid & 15;
            float s0 = 0.f, s1 = 0.f;
            for (int d = 0; d < DQK; ++d) {
                const float b = Ks[j][d];
                s0 = fmaf(Qs[i0][d], b, s0);
                s1 = fmaf(Qs[i0 + 1][d], b, s1);
            }
            const float sc = 0.07216878364870322f;  // 1/sqrt(192)
            const int kg = k0 + j;
            Ssh[i0][j]     = (q0 + i0     >= kg) ? s0 * sc : -3.0e38f;
            Ssh[i0 + 1][j] = (q0 + i0 + 1 >= kg) ? s1 * sc : -3.0e38f;
        }
        __syncthreads();
        if (tid < BM) {
            const int r = tid;
            const float mo = mrow[r];
            float mx = mo;
            for (int j = 0; j < BN; ++j) mx = fmaxf(mx, Ssh[r][j]);
            const float al = __expf(mo - mx);
            float sum = 0.f;
            for (int j = 0; j < BN; ++j) {
                const float p = __expf(Ssh[r][j] - mx);
                Ssh[r][j] = p;
                sum += p;
            }
            mrow[r] = mx;
            lrow[r] = lrow[r] * al + sum;
            arow[r] = al;
        }
        __syncthreads();
        {
            const float al = arow[orow];
#pragma unroll
            for (int d = 0; d < 16; ++d) o[d] *= al;
            for (int j = 0; j < BN; ++j) {
                const float p = Ssh[orow][j];
#pragma unroll
                for (int d = 0; d < 16; ++d)
                    o[d] = fmaf(p, Vs[j][oc0 + d], o[d]);
            }
        }
    }
    __syncthreads();
    const float linv = 1.f / lrow[orow];
    float* op = attn + (size_t)(q0 + orow) * (NH * DV) + h * DV + oc0;
#pragma unroll
    for (int d = 0; d < 16; ++d) op[d] = o[d] * linv;
}

extern "C" void kernel_launch(void* const* d_in, const int* in_sizes, int n_in,
                              void* d_out, int out_size, void* d_ws, size_t ws_size,
                              hipStream_t stream)
{
    const int*   positions = (const int*)d_in[0];
    const float* hidden    = (const float*)d_in[1];
    const float* scaling   = (const float*)d_in[2];
    const float* w_q_a     = (const float*)d_in[3];
    const float* q_a_ln_w  = (const float*)d_in[4];
    const float* w_q_b     = (const float*)d_in[5];
    const float* w_kv_a    = (const float*)d_in[6];
    const float* kv_a_ln_w = (const float*)d_in[7];
    const float* w_kv_b    = (const float*)d_in[8];
    const float* w_o       = (const float*)d_in[9];
    const float* cs_cache  = (const float*)d_in[10];
    float* out = (float*)d_out;

    float* ws = (float*)d_ws;
    float* q_a    = ws;                                        // T*QRANK
    float* qbuf   = q_a    + (size_t)T_TOK * QRANK;            // T*NH*DQK
    float* latent = qbuf   + (size_t)T_TOK * NH * DQK;         // T*(KVRANK+DR)
    float* kpe    = latent + (size_t)T_TOK * (KVRANK + DR);    // T*DR
    float* kvbuf  = kpe    + (size_t)T_TOK * DR;               // T*NH*(DN+DV)
    float* attnb  = kvbuf  + (size_t)T_TOK * NH * (DN + DV);   // T*NH*DV

    const dim3 blk(256);

    // q_a = hidden @ w_q_a   (3072x5120 @ 5120x1536)
    sgemm_k<<<dim3(QRANK / 128, T_TOK / 128), blk, 0, stream>>>(
        hidden, w_q_a, q_a, T_TOK, QRANK, HID_D, HID_D, QRANK, QRANK);
    // latent = hidden @ w_kv_a  (3072x5120 @ 5120x576)
    sgemm_k<<<dim3((KVRANK + DR + 127) / 128, T_TOK / 128), blk, 0, stream>>>(
        hidden, w_kv_a, latent, T_TOK, KVRANK + DR, HID_D, HID_D, KVRANK + DR, KVRANK + DR);
    // k_pe rope from pre-norm latent tail
    rope_k_k<<<dim3(T_TOK), dim3(64), 0, stream>>>(latent, kpe, positions, cs_cache);
    // rmsnorms
    rmsnorm_k<<<dim3(T_TOK), blk, 0, stream>>>(q_a, q_a_ln_w, QRANK, QRANK);
    rmsnorm_k<<<dim3(T_TOK), blk, 0, stream>>>(latent, kv_a_ln_w, KVRANK, KVRANK + DR);
    // q = q_a_norm @ w_q_b   (3072x1536 @ 1536x3072)
    sgemm_k<<<dim3(NH * DQK / 128, T_TOK / 128), blk, 0, stream>>>(
        q_a, w_q_b, qbuf, T_TOK, NH * DQK, QRANK, QRANK, NH * DQK, NH * DQK);
    // rope + llama4 scaling on q
    rope_scale_q_k<<<dim3(T_TOK), dim3(256), 0, stream>>>(qbuf, positions, scaling, cs_cache);
    // kv = kv_a_norm @ w_kv_b  (3072x512 @ 512x4096), A has row stride 576
    sgemm_k<<<dim3(NH * (DN + DV) / 128, T_TOK / 128), blk, 0, stream>>>(
        latent, w_kv_b, kvbuf, T_TOK, NH * (DN + DV), KVRANK, KVRANK + DR,
        NH * (DN + DV), NH * (DN + DV));
    // causal flash attention
    attn_k<<<dim3(T_TOK / BM, NH), blk, 0, stream>>>(qbuf, kvbuf, kpe, attnb);
    // out = attn @ w_o  (3072x2048 @ 2048x5120)
    sgemm_k<<<dim3(HID_D / 128, T_TOK / 128), blk, 0, stream>>>(
        attnb, w_o, out, T_TOK, HID_D, NH * DV, NH * DV, HID_D, HID_D);
}

// Round 2
// 4119.417 us; speedup vs baseline: 1.6698x; 1.6698x over previous
//
#include <hip/hip_runtime.h>
#include <hip/hip_bf16.h>
#include <math.h>

#define T_TOK 3072
#define HID_D 5120
#define NH 16
#define DN 128
#define DR 64
#define DQK 192
#define DV 128
#define QRANK 1536
#define KVRANK 512

typedef __attribute__((ext_vector_type(8))) short short8;
typedef __attribute__((ext_vector_type(4))) float f32x4;
typedef unsigned short u16;

__device__ inline u16 f2bf(float f) {
    unsigned int u = __float_as_uint(f);
    unsigned int lsb = (u >> 16) & 1;
    u += 0x7fffu + lsb;
    return (u16)(u >> 16);
}

// ---------------- generic fp32 tiled GEMM: C = A @ B ----------------
__global__ __launch_bounds__(256) void sgemm_k(
    const float* __restrict__ A, const float* __restrict__ B, float* __restrict__ C,
    int M, int N, int K, int lda, int ldb, int ldc)
{
    __shared__ float As[8][132];
    __shared__ float Bs[8][132];
    const int tid  = threadIdx.x;
    const int row0 = blockIdx.y * 128;
    const int col0 = blockIdx.x * 128;

    float acc[8][8];
#pragma unroll
    for (int i = 0; i < 8; ++i)
#pragma unroll
        for (int j = 0; j < 8; ++j) acc[i][j] = 0.f;

    const int tm = (tid >> 4) << 3;
    const int tn = (tid & 15) << 3;
    const int ar = tid >> 1;
    const int ak = (tid & 1) << 2;
    const int bk = tid >> 5;
    const int bn = (tid & 31) << 2;

    for (int kt = 0; kt < K; kt += 8) {
        const float* ap = A + (size_t)(row0 + ar) * lda + kt + ak;
        float4 av = *(const float4*)ap;
        As[ak + 0][ar] = av.x;
        As[ak + 1][ar] = av.y;
        As[ak + 2][ar] = av.z;
        As[ak + 3][ar] = av.w;
        float4 bv;
        const int bcol = col0 + bn;
        const float* bp = B + (size_t)(kt + bk) * ldb + bcol;
        if (bcol + 3 < N) {
            bv = *(const float4*)bp;
        } else {
            bv.x = (bcol + 0 < N) ? bp[0] : 0.f;
            bv.y = (bcol + 1 < N) ? bp[1] : 0.f;
            bv.z = (bcol + 2 < N) ? bp[2] : 0.f;
            bv.w = (bcol + 3 < N) ? bp[3] : 0.f;
        }
        *(float4*)&Bs[bk][bn] = bv;
        __syncthreads();

#pragma unroll
        for (int k = 0; k < 8; ++k) {
            float af[8], bf[8];
#pragma unroll
            for (int i = 0; i < 8; ++i) af[i] = As[k][tm + i];
#pragma unroll
            for (int j = 0; j < 8; ++j) bf[j] = Bs[k][tn + j];
#pragma unroll
            for (int i = 0; i < 8; ++i)
#pragma unroll
                for (int j = 0; j < 8; ++j)
                    acc[i][j] = fmaf(af[i], bf[j], acc[i][j]);
        }
        __syncthreads();
    }

#pragma unroll
    for (int i = 0; i < 8; ++i) {
        const int r = row0 + tm + i;
        float* cp = C + (size_t)r * ldc + col0 + tn;
#pragma unroll
        for (int j = 0; j < 8; ++j) {
            const int c = col0 + tn + j;
            if (c < N) cp[j] = acc[i][j];
        }
    }
}

// ---------------- RMSNorm (in place) ----------------
__global__ __launch_bounds__(256) void rmsnorm_k(float* __restrict__ x,
                                                 const float* __restrict__ w,
                                                 int width, int stride)
{
    const int row = blockIdx.x;
    float* xr = x + (size_t)row * stride;
    float ss = 0.f;
    for (int i = threadIdx.x; i < width; i += 256) {
        float v = xr[i];
        ss += v * v;
    }
    __shared__ float red[256];
    red[threadIdx.x] = ss;
    __syncthreads();
    for (int s = 128; s > 0; s >>= 1) {
        if (threadIdx.x < s) red[threadIdx.x] += red[threadIdx.x + s];
        __syncthreads();
    }
    const float scale = rsqrtf(red[0] / (float)width + 1e-6f);
    for (int i = threadIdx.x; i < width; i += 256) xr[i] = xr[i] * scale * w[i];
}

// ---------------- RoPE on q_pe + llama_4 scaling ----------------
__global__ void rope_scale_q_k(float* __restrict__ q, const int* __restrict__ positions,
                               const float* __restrict__ scaling,
                               const float* __restrict__ cs_cache)
{
    const int t = blockIdx.x;
    const int pos = positions[t];
    const float* cs = cs_cache + (size_t)pos * DR;
    const float s = scaling[t];
    __shared__ float c_sh[32], s_sh[32];
    if (threadIdx.x < 32) {
        c_sh[threadIdx.x] = cs[threadIdx.x];
        s_sh[threadIdx.x] = cs[32 + threadIdx.x];
    }
    __syncthreads();
    for (int h = 0; h < NH; ++h) {
        float* qr = q + ((size_t)t * NH + h) * DQK;
        const int tid = threadIdx.x;
        if (tid < 128) {
            qr[tid] *= s;
        } else if (tid < 160) {
            const int d = tid - 128;
            const float x1 = qr[128 + d], x2 = qr[160 + d];
            qr[128 + d] = (x1 * c_sh[d] - x2 * s_sh[d]) * s;
            qr[160 + d] = (x2 * c_sh[d] + x1 * s_sh[d]) * s;
        }
    }
}

// ---------------- RoPE on k_pe ----------------
__global__ void rope_k_k(const float* __restrict__ latent, float* __restrict__ kpe,
                         const int* __restrict__ positions,
                         const float* __restrict__ cs_cache)
{
    const int t = blockIdx.x;
    const int d = threadIdx.x;
    if (d >= 32) return;
    const int pos = positions[t];
    const float* cs = cs_cache + (size_t)pos * DR;
    const float c = cs[d], sn = cs[32 + d];
    const float* lr = latent + (size_t)t * (KVRANK + DR) + KVRANK;
    const float x1 = lr[d], x2 = lr[32 + d];
    kpe[(size_t)t * DR + d]      = x1 * c - x2 * sn;
    kpe[(size_t)t * DR + 32 + d] = x2 * c + x1 * sn;
}

// ---------------- fp32 -> bf16 conversion: build qb, kb, vb ----------------
// qb: (T, NH, 192)  kb: (T, NH, 192) = [k_nope | k_pe broadcast]  vb: (T, NH, 128)
__global__ void convert_k(const float* __restrict__ qf, const float* __restrict__ kvf,
                          const float* __restrict__ kpef,
                          u16* __restrict__ qb, u16* __restrict__ kb, u16* __restrict__ vb)
{
    const int th = blockIdx.x;           // t*NH + h
    const int t = th / NH;
    const int d = threadIdx.x;           // 0..191
    qb[(size_t)th * DQK + d] = f2bf(qf[(size_t)th * DQK + d]);
    if (d < DN) {
        kb[(size_t)th * DQK + d] = f2bf(kvf[(size_t)th * (DN + DV) + d]);
        vb[(size_t)th * DV + d]  = f2bf(kvf[(size_t)th * (DN + DV) + DN + d]);
    } else {
        kb[(size_t)th * DQK + d] = f2bf(kpef[(size_t)t * DR + (d - DN)]);
    }
}

// ---------------- bf16 MFMA flash attention ----------------
// Block: 256 threads = 4 waves. BM=64 q-rows/block (16/wave), BN=64 keys/iter.
// mfma_f32_16x16x32_bf16: A[m=lane&15][k=quad*8+j], B[k=quad*8+j][n=lane&15],
// C/D: col=lane&15, row=quad*4+reg.
#define ATT_BM 64
#define ATT_BN 64
__global__ __launch_bounds__(256) void attn_mfma_k(
    const u16* __restrict__ qb, const u16* __restrict__ kb,
    const u16* __restrict__ vb, float* __restrict__ attn)
{
    __shared__ u16 Ks[ATT_BN][200];    // 192 + 8 pad (row = 400 B, 16B-aligned)
    __shared__ u16 Vt[DV][72];         // transposed V: [dv_col][key], 144 B rows
    __shared__ u16 Ps[4][16][72];      // per-wave P, 144 B rows

    const int tid  = threadIdx.x;
    const int wave = tid >> 6;
    const int lane = tid & 63;
    const int quad = lane >> 4;
    const int l16  = lane & 15;

    const int qblk = blockIdx.x;
    const int h    = blockIdx.y;
    const int q0   = qblk * ATT_BM;
    const int qrow = q0 + wave * 16 + l16;   // this lane's A-operand row

    // Q fragments for 6 k-chunks of 32, held in registers for the whole block
    short8 qf[6];
    {
        const u16* qp = qb + ((size_t)qrow * NH + h) * DQK + quad * 8;
#pragma unroll
        for (int c = 0; c < 6; ++c)
            qf[c] = *(const short8*)(qp + c * 32);
    }

    f32x4 oacc[8];
#pragma unroll
    for (int t = 0; t < 8; ++t) oacc[t] = (f32x4){0.f, 0.f, 0.f, 0.f};
    float m_old[4], l_run[4];
#pragma unroll
    for (int r = 0; r < 4; ++r) { m_old[r] = -1e30f; l_run[r] = 0.f; }

    const int nkt = qblk + 1;
    for (int kt = 0; kt < nkt; ++kt) {
        const int k0 = kt * ATT_BN;
        __syncthreads();   // protect Ks/Vt reuse from previous iteration
        // stage K tile: 64 rows x 192 bf16
        for (int cc = tid; cc < 64 * 24; cc += 256) {
            const int row = cc / 24, pos = (cc % 24) * 8;
            const u16* src = kb + ((size_t)(k0 + row) * NH + h) * DQK + pos;
            *(short8*)&Ks[row][pos] = *(const short8*)src;
        }
        // stage V transposed: lane j handles key row j, wave w covers dv cols w*32..+31
        {
            const int j  = tid & 63;
            const int db = (tid >> 6) * 32;
            const u16* src = vb + ((size_t)(k0 + j) * NH + h) * DV + db;
#pragma unroll
            for (int i = 0; i < 32; i += 4) {
                ushort4 v4 = *(const ushort4*)(src + i);
                Vt[db + i + 0][j] = v4.x;
                Vt[db + i + 1][j] = v4.y;
                Vt[db + i + 2][j] = v4.z;
                Vt[db + i + 3][j] = v4.w;
            }
        }
        __syncthreads();

        // S = Q K^T : 4 col-tiles of 16 keys x 6 chunks of k=32
        f32x4 sacc[4];
#pragma unroll
        for (int t = 0; t < 4; ++t) sacc[t] = (f32x4){0.f, 0.f, 0.f, 0.f};
#pragma unroll
        for (int t = 0; t < 4; ++t) {
            const u16* kp = &Ks[t * 16 + l16][quad * 8];
#pragma unroll
            for (int c = 0; c < 6; ++c) {
                short8 bfrag = *(const short8*)(kp + c * 32);
                sacc[t] = __builtin_amdgcn_mfma_f32_16x16x32_bf16(qf[c], bfrag, sacc[t], 0, 0, 0);
            }
        }
        // scale + causal mask
        const float sc = 0.07216878364870322f;   // 1/sqrt(192)
        const int rbase = q0 + wave * 16 + quad * 4;
#pragma unroll
        for (int t = 0; t < 4; ++t) {
            const int colg = k0 + t * 16 + l16;
#pragma unroll
            for (int r = 0; r < 4; ++r) {
                const float s = sacc[t][r] * sc;
                sacc[t][r] = (rbase + r >= colg) ? s : -1e30f;
            }
        }
        // online softmax, rows live on 16-lane groups
        float alpha[4];
#pragma unroll
        for (int r = 0; r < 4; ++r) {
            float mx = fmaxf(fmaxf(sacc[0][r], sacc[1][r]), fmaxf(sacc[2][r], sacc[3][r]));
            mx = fmaxf(mx, __shfl_xor(mx, 1));
            mx = fmaxf(mx, __shfl_xor(mx, 2));
            mx = fmaxf(mx, __shfl_xor(mx, 4));
            mx = fmaxf(mx, __shfl_xor(mx, 8));
            const float mnew = fmaxf(m_old[r], mx);
            alpha[r] = __expf(m_old[r] - mnew);
            float sum = 0.f;
#pragma unroll
            for (int t = 0; t < 4; ++t) {
                const float p = __expf(sacc[t][r] - mnew);
                sacc[t][r] = p;
                sum += p;
            }
            sum += __shfl_xor(sum, 1);
            sum += __shfl_xor(sum, 2);
            sum += __shfl_xor(sum, 4);
            sum += __shfl_xor(sum, 8);
            l_run[r] = l_run[r] * alpha[r] + sum;
            m_old[r] = mnew;
        }
        // write P (C-layout) to LDS as bf16
#pragma unroll
        for (int t = 0; t < 4; ++t)
#pragma unroll
            for (int r = 0; r < 4; ++r)
                Ps[wave][quad * 4 + r][t * 16 + l16] = f2bf(sacc[t][r]);
        // rescale O accumulators
#pragma unroll
        for (int t = 0; t < 8; ++t)
#pragma unroll
            for (int r = 0; r < 4; ++r)
                oacc[t][r] *= alpha[r];
        __syncthreads();   // ensure P writes visible before A-layout reads

        // O += P V : P is A-operand (16x64), V B-operand via transposed LDS
#pragma unroll
        for (int ch = 0; ch < 2; ++ch) {
            short8 pfrag = *(const short8*)&Ps[wave][l16][ch * 32 + quad * 8];
#pragma unroll
            for (int t = 0; t < 8; ++t) {
                short8 vfrag = *(const short8*)&Vt[t * 16 + l16][ch * 32 + quad * 8];
                oacc[t] = __builtin_amdgcn_mfma_f32_16x16x32_bf16(pfrag, vfrag, oacc[t], 0, 0, 0);
            }
        }
    }

    // epilogue: divide by l, store fp32
#pragma unroll
    for (int r = 0; r < 4; ++r) {
        const float linv = 1.f / l_run[r];
        const int row_g = q0 + wave * 16 + quad * 4 + r;
        float* op = attn + (size_t)row_g * (NH * DV) + h * DV;
#pragma unroll
        for (int t = 0; t < 8; ++t)
            op[t * 16 + l16] = oacc[t][r] * linv;
    }
}

extern "C" void kernel_launch(void* const* d_in, const int* in_sizes, int n_in,
                              void* d_out, int out_size, void* d_ws, size_t ws_size,
                              hipStream_t stream)
{
    const int*   positions = (const int*)d_in[0];
    const float* hidden    = (const float*)d_in[1];
    const float* scaling   = (const float*)d_in[2];
    const float* w_q_a     = (const float*)d_in[3];
    const float* q_a_ln_w  = (const float*)d_in[4];
    const float* w_q_b     = (const float*)d_in[5];
    const float* w_kv_a    = (const float*)d_in[6];
    const float* kv_a_ln_w = (const float*)d_in[7];
    const float* w_kv_b    = (const float*)d_in[8];
    const float* w_o       = (const float*)d_in[9];
    const float* cs_cache  = (const float*)d_in[10];
    float* out = (float*)d_out;

    float* ws = (float*)d_ws;
    float* q_a    = ws;                                        // T*QRANK
    float* qbuf   = q_a    + (size_t)T_TOK * QRANK;            // T*NH*DQK
    float* latent = qbuf   + (size_t)T_TOK * NH * DQK;         // T*(KVRANK+DR)
    float* kpe    = latent + (size_t)T_TOK * (KVRANK + DR);    // T*DR
    float* kvbuf  = kpe    + (size_t)T_TOK * DR;               // T*NH*(DN+DV)
    float* attnb  = kvbuf  + (size_t)T_TOK * NH * (DN + DV);   // T*NH*DV
    u16*   qb     = (u16*)(attnb + (size_t)T_TOK * NH * DV);   // T*NH*DQK bf16
    u16*   kb     = qb + (size_t)T_TOK * NH * DQK;             // T*NH*DQK bf16
    u16*   vb     = kb + (size_t)T_TOK * NH * DQK;             // T*NH*DV bf16

    const dim3 blk(256);

    sgemm_k<<<dim3(QRANK / 128, T_TOK / 128), blk, 0, stream>>>(
        hidden, w_q_a, q_a, T_TOK, QRANK, HID_D, HID_D, QRANK, QRANK);
    sgemm_k<<<dim3((KVRANK + DR + 127) / 128, T_TOK / 128), blk, 0, stream>>>(
        hidden, w_kv_a, latent, T_TOK, KVRANK + DR, HID_D, HID_D, KVRANK + DR, KVRANK + DR);
    rope_k_k<<<dim3(T_TOK), dim3(64), 0, stream>>>(latent, kpe, positions, cs_cache);
    rmsnorm_k<<<dim3(T_TOK), blk, 0, stream>>>(q_a, q_a_ln_w, QRANK, QRANK);
    rmsnorm_k<<<dim3(T_TOK), blk, 0, stream>>>(latent, kv_a_ln_w, KVRANK, KVRANK + DR);
    sgemm_k<<<dim3(NH * DQK / 128, T_TOK / 128), blk, 0, stream>>>(
        q_a, w_q_b, qbuf, T_TOK, NH * DQK, QRANK, QRANK, NH * DQK, NH * DQK);
    rope_scale_q_k<<<dim3(T_TOK), dim3(256), 0, stream>>>(qbuf, positions, scaling, cs_cache);
    sgemm_k<<<dim3(NH * (DN + DV) / 128, T_TOK / 128), blk, 0, stream>>>(
        latent, w_kv_b, kvbuf, T_TOK, NH * (DN + DV), KVRANK, KVRANK + DR,
        NH * (DN + DV), NH * (DN + DV));
    // build bf16 Q/K/V for MFMA attention
    convert_k<<<dim3(T_TOK * NH), dim3(DQK), 0, stream>>>(qbuf, kvbuf, kpe, qb, kb, vb);
    // flash attention (bf16 MFMA)
    attn_mfma_k<<<dim3(T_TOK / ATT_BM, NH), blk, 0, stream>>>(qb, kb, vb, attnb);
    // out = attn @ w_o
    sgemm_k<<<dim3(HID_D / 128, T_TOK / 128), blk, 0, stream>>>(
        attnb, w_o, out, T_TOK, HID_D, NH * DV, NH * DV, HID_D, HID_D);
}

// Round 3
// 925.471 us; speedup vs baseline: 7.4325x; 4.4512x over previous
//
#include <hip/hip_runtime.h>
#include <hip/hip_bf16.h>
#include <math.h>

#define T_TOK 3072
#define HID_D 5120
#define NH 16
#define DN 128
#define DR 64
#define DQK 192
#define DV 128
#define QRANK 1536
#define KVRANK 512

typedef __attribute__((ext_vector_type(8))) short short8;
typedef __attribute__((ext_vector_type(4))) float f32x4;
typedef unsigned short u16;

__device__ __forceinline__ u16 f2bf(float f) {
    unsigned int u = __float_as_uint(f);
    unsigned int lsb = (u >> 16) & 1;
    u += 0x7fffu + lsb;
    return (u16)(u >> 16);
}

__device__ __forceinline__ void gload_lds16(const u16* g, u16* l) {
    __builtin_amdgcn_global_load_lds((const __attribute__((address_space(1))) void*)g,
                                     (__attribute__((address_space(3))) void*)l, 16, 0, 0);
}

// ---------------- fp32 -> bf16 elementwise (vectorized) ----------------
__global__ __launch_bounds__(256) void convert_bf_k(const float* __restrict__ x,
                                                    u16* __restrict__ y, int n4)
{
    const int i = blockIdx.x * 256 + threadIdx.x;
    if (i < n4) {
        float4 v = ((const float4*)x)[i];
        ushort4 o;
        o.x = f2bf(v.x); o.y = f2bf(v.y); o.z = f2bf(v.z); o.w = f2bf(v.w);
        ((ushort4*)y)[i] = o;
    }
}

// ---------------- fp32 K x N  ->  bf16 Npad x K (transposed, zero-padded) ----------------
__global__ __launch_bounds__(256) void transpose_conv_k(const float* __restrict__ W,
                                                        u16* __restrict__ WT,
                                                        int K, int N)
{
    __shared__ float tile[32][33];
    const int n0 = blockIdx.x * 32, k0 = blockIdx.y * 32;
    const int tx = threadIdx.x & 31, ty = threadIdx.x >> 5;  // ty 0..7
#pragma unroll
    for (int i = 0; i < 32; i += 8) {
        const int nn = n0 + tx;
        tile[ty + i][tx] = (nn < N) ? W[(size_t)(k0 + ty + i) * N + nn] : 0.f;
    }
    __syncthreads();
#pragma unroll
    for (int i = 0; i < 32; i += 8) {
        WT[(size_t)(n0 + ty + i) * K + k0 + tx] = f2bf(tile[tx][ty + i]);
    }
}

// ---------------- bf16 MFMA GEMM, B transposed: C = A @ BT^T ----------------
// A: M x K bf16 (lda), BT: Npad x K bf16 (ldb), C: M x N (ldc) fp32 or bf16.
// 128x128 tile, BK=32, 256 thr = 4 waves (2x2 of 64x64), m97 structure.
template <bool BF16_OUT>
__global__ __launch_bounds__(256) void bgemm_bt_k(
    const u16* __restrict__ A, const u16* __restrict__ BT, void* __restrict__ C,
    int Nreal, int K, int lda, int ldb, int ldc)
{
    __shared__ __attribute__((aligned(16))) u16 As[128 * 32];
    __shared__ __attribute__((aligned(16))) u16 Bs[128 * 32];

    const int tid  = threadIdx.x;
    const int wave = tid >> 6, lane = tid & 63;
    const int quad = lane >> 4, l16 = lane & 15;
    const int wr = (wave >> 1) * 64, wc = (wave & 1) * 64;
    const int row0 = blockIdx.y * 128, col0 = blockIdx.x * 128;

    f32x4 acc[4][4];
#pragma unroll
    for (int i = 0; i < 4; ++i)
#pragma unroll
        for (int j = 0; j < 4; ++j) acc[i][j] = (f32x4){0.f, 0.f, 0.f, 0.f};

    // staging: thread covers 16B at LDS offset tid*16 and tid*16+4096
    const int sr  = tid >> 2;            // 0..63 (tile row)
    const int skc = (tid & 3) * 8;       // k-chunk offset (bf16 elems)
    const u16* ap0 = A  + (size_t)(row0 + sr)      * lda + skc;
    const u16* ap1 = A  + (size_t)(row0 + sr + 64) * lda + skc;
    const u16* bp0 = BT + (size_t)(col0 + sr)      * ldb + skc;
    const u16* bp1 = BT + (size_t)(col0 + sr + 64) * ldb + skc;
    u16* al0 = As + tid * 8;
    u16* al1 = As + tid * 8 + 64 * 32;
    u16* bl0 = Bs + tid * 8;
    u16* bl1 = Bs + tid * 8 + 64 * 32;

    for (int kt = 0; kt < K; kt += 32) {
        gload_lds16(ap0 + kt, al0);
        gload_lds16(ap1 + kt, al1);
        gload_lds16(bp0 + kt, bl0);
        gload_lds16(bp1 + kt, bl1);
        __syncthreads();   // drains vmcnt, loads visible

        short8 af[4], bf[4];
#pragma unroll
        for (int mi = 0; mi < 4; ++mi)
            af[mi] = *(const short8*)(As + (wr + mi * 16 + l16) * 32 + quad * 8);
#pragma unroll
        for (int ni = 0; ni < 4; ++ni)
            bf[ni] = *(const short8*)(Bs + (wc + ni * 16 + l16) * 32 + quad * 8);
#pragma unroll
        for (int mi = 0; mi < 4; ++mi)
#pragma unroll
            for (int ni = 0; ni < 4; ++ni)
                acc[mi][ni] = __builtin_amdgcn_mfma_f32_16x16x32_bf16(
                    af[mi], bf[ni], acc[mi][ni], 0, 0, 0);
        __syncthreads();   // protect LDS before next overwrite
    }

#pragma unroll
    for (int mi = 0; mi < 4; ++mi) {
#pragma unroll
        for (int ni = 0; ni < 4; ++ni) {
            const int col_g = col0 + wc + ni * 16 + l16;
            if (col_g < Nreal) {
#pragma unroll
                for (int r = 0; r < 4; ++r) {
                    const int row_g = row0 + wr + mi * 16 + quad * 4 + r;
                    if (BF16_OUT)
                        ((u16*)C)[(size_t)row_g * ldc + col_g] = f2bf(acc[mi][ni][r]);
                    else
                        ((float*)C)[(size_t)row_g * ldc + col_g] = acc[mi][ni][r];
                }
            }
        }
    }
}

// ---------------- RMSNorm: fp32 strided in -> bf16 compact out ----------------
__global__ __launch_bounds__(256) void rmsnorm_conv_k(const float* __restrict__ x,
                                                      const float* __restrict__ w,
                                                      u16* __restrict__ y,
                                                      int width, int stride)
{
    const int row = blockIdx.x;
    const float* xr = x + (size_t)row * stride;
    float ss = 0.f;
    for (int i = threadIdx.x; i < width; i += 256) {
        float v = xr[i];
        ss += v * v;
    }
    __shared__ float red[256];
    red[threadIdx.x] = ss;
    __syncthreads();
    for (int s = 128; s > 0; s >>= 1) {
        if (threadIdx.x < s) red[threadIdx.x] += red[threadIdx.x + s];
        __syncthreads();
    }
    const float scale = rsqrtf(red[0] / (float)width + 1e-6f);
    for (int i = threadIdx.x; i < width; i += 256)
        y[(size_t)row * width + i] = f2bf(xr[i] * scale * w[i]);
}

// ---------------- RoPE on q (fp32 in) + llama_4 scaling -> bf16 out ----------------
__global__ void rope_scale_q_conv_k(const float* __restrict__ q, const int* __restrict__ positions,
                                    const float* __restrict__ scaling,
                                    const float* __restrict__ cs_cache, u16* __restrict__ qb)
{
    const int t = blockIdx.x;
    const int pos = positions[t];
    const float* cs = cs_cache + (size_t)pos * DR;
    const float s = scaling[t];
    __shared__ float c_sh[32], s_sh[32];
    if (threadIdx.x < 32) {
        c_sh[threadIdx.x] = cs[threadIdx.x];
        s_sh[threadIdx.x] = cs[32 + threadIdx.x];
    }
    __syncthreads();
    const int tid = threadIdx.x;
    for (int h = 0; h < NH; ++h) {
        const float* qr = q + ((size_t)t * NH + h) * DQK;
        u16* qo = qb + ((size_t)t * NH + h) * DQK;
        if (tid < 128) {
            qo[tid] = f2bf(qr[tid] * s);
        } else if (tid < 160) {
            const int d = tid - 128;
            const float x1 = qr[128 + d], x2 = qr[160 + d];
            qo[128 + d] = f2bf((x1 * c_sh[d] - x2 * s_sh[d]) * s);
            qo[160 + d] = f2bf((x2 * c_sh[d] + x1 * s_sh[d]) * s);
        }
    }
}

// ---------------- RoPE on k_pe (pre-norm latent tail, fp32) -> bf16 ----------------
__global__ void rope_k_conv_k(const float* __restrict__ latent, u16* __restrict__ kpe,
                              const int* __restrict__ positions,
                              const float* __restrict__ cs_cache)
{
    const int t = blockIdx.x;
    const int d = threadIdx.x;
    if (d >= 32) return;
    const int pos = positions[t];
    const float* cs = cs_cache + (size_t)pos * DR;
    const float c = cs[d], sn = cs[32 + d];
    const float* lr = latent + (size_t)t * (KVRANK + DR) + KVRANK;
    const float x1 = lr[d], x2 = lr[32 + d];
    kpe[(size_t)t * DR + d]      = f2bf(x1 * c - x2 * sn);
    kpe[(size_t)t * DR + 32 + d] = f2bf(x2 * c + x1 * sn);
}

// ---------------- bf16 MFMA flash attention ----------------
// qb: (T,NH,192)  kvb: (T,NH,256)=[k_nope|v]  kpeb: (T,64)  attnb: (T,NH*128) bf16
#define ATT_BM 64
#define ATT_BN 64
__global__ __launch_bounds__(256) void attn_mfma_k(
    const u16* __restrict__ qb, const u16* __restrict__ kvb,
    const u16* __restrict__ kpeb, u16* __restrict__ attnb)
{
    __shared__ u16 Ks[ATT_BN][200];
    __shared__ u16 Vt[DV][72];
    __shared__ u16 Ps[4][16][72];

    const int tid  = threadIdx.x;
    const int wave = tid >> 6;
    const int lane = tid & 63;
    const int quad = lane >> 4;
    const int l16  = lane & 15;

    const int qblk = blockIdx.x;
    const int h    = blockIdx.y;
    const int q0   = qblk * ATT_BM;
    const int qrow = q0 + wave * 16 + l16;

    short8 qf[6];
    {
        const u16* qp = qb + ((size_t)qrow * NH + h) * DQK + quad * 8;
#pragma unroll
        for (int c = 0; c < 6; ++c)
            qf[c] = *(const short8*)(qp + c * 32);
    }

    f32x4 oacc[8];
#pragma unroll
    for (int t = 0; t < 8; ++t) oacc[t] = (f32x4){0.f, 0.f, 0.f, 0.f};
    float m_old[4], l_run[4];
#pragma unroll
    for (int r = 0; r < 4; ++r) { m_old[r] = -1e30f; l_run[r] = 0.f; }

    const int nkt = qblk + 1;
    for (int kt = 0; kt < nkt; ++kt) {
        const int k0 = kt * ATT_BN;
        __syncthreads();
        for (int cc = tid; cc < 64 * 24; cc += 256) {
            const int row = cc / 24, c = cc % 24;
            short8 v;
            if (c < 16) v = *(const short8*)(kvb + ((size_t)(k0 + row) * NH + h) * (DN + DV) + c * 8);
            else        v = *(const short8*)(kpeb + (size_t)(k0 + row) * DR + (c - 16) * 8);
            *(short8*)&Ks[row][c * 8] = v;
        }
        {
            const int j  = tid & 63;
            const int db = (tid >> 6) * 32;
            const u16* src = kvb + ((size_t)(k0 + j) * NH + h) * (DN + DV) + DN + db;
#pragma unroll
            for (int i = 0; i < 32; i += 4) {
                ushort4 v4 = *(const ushort4*)(src + i);
                Vt[db + i + 0][j] = v4.x;
                Vt[db + i + 1][j] = v4.y;
                Vt[db + i + 2][j] = v4.z;
                Vt[db + i + 3][j] = v4.w;
            }
        }
        __syncthreads();

        f32x4 sacc[4];
#pragma unroll
        for (int t = 0; t < 4; ++t) sacc[t] = (f32x4){0.f, 0.f, 0.f, 0.f};
#pragma unroll
        for (int t = 0; t < 4; ++t) {
            const u16* kp = &Ks[t * 16 + l16][quad * 8];
#pragma unroll
            for (int c = 0; c < 6; ++c) {
                short8 bfrag = *(const short8*)(kp + c * 32);
                sacc[t] = __builtin_amdgcn_mfma_f32_16x16x32_bf16(qf[c], bfrag, sacc[t], 0, 0, 0);
            }
        }
        const float sc = 0.07216878364870322f;
        const int rbase = q0 + wave * 16 + quad * 4;
#pragma unroll
        for (int t = 0; t < 4; ++t) {
            const int colg = k0 + t * 16 + l16;
#pragma unroll
            for (int r = 0; r < 4; ++r) {
                const float s = sacc[t][r] * sc;
                sacc[t][r] = (rbase + r >= colg) ? s : -1e30f;
            }
        }
        float alpha[4];
#pragma unroll
        for (int r = 0; r < 4; ++r) {
            float mx = fmaxf(fmaxf(sacc[0][r], sacc[1][r]), fmaxf(sacc[2][r], sacc[3][r]));
            mx = fmaxf(mx, __shfl_xor(mx, 1));
            mx = fmaxf(mx, __shfl_xor(mx, 2));
            mx = fmaxf(mx, __shfl_xor(mx, 4));
            mx = fmaxf(mx, __shfl_xor(mx, 8));
            const float mnew = fmaxf(m_old[r], mx);
            alpha[r] = __expf(m_old[r] - mnew);
            float sum = 0.f;
#pragma unroll
            for (int t = 0; t < 4; ++t) {
                const float p = __expf(sacc[t][r] - mnew);
                sacc[t][r] = p;
                sum += p;
            }
            sum += __shfl_xor(sum, 1);
            sum += __shfl_xor(sum, 2);
            sum += __shfl_xor(sum, 4);
            sum += __shfl_xor(sum, 8);
            l_run[r] = l_run[r] * alpha[r] + sum;
            m_old[r] = mnew;
        }
#pragma unroll
        for (int t = 0; t < 4; ++t)
#pragma unroll
            for (int r = 0; r < 4; ++r)
                Ps[wave][quad * 4 + r][t * 16 + l16] = f2bf(sacc[t][r]);
#pragma unroll
        for (int t = 0; t < 8; ++t)
#pragma unroll
            for (int r = 0; r < 4; ++r)
                oacc[t][r] *= alpha[r];
        __syncthreads();

#pragma unroll
        for (int ch = 0; ch < 2; ++ch) {
            short8 pfrag = *(const short8*)&Ps[wave][l16][ch * 32 + quad * 8];
#pragma unroll
            for (int t = 0; t < 8; ++t) {
                short8 vfrag = *(const short8*)&Vt[t * 16 + l16][ch * 32 + quad * 8];
                oacc[t] = __builtin_amdgcn_mfma_f32_16x16x32_bf16(pfrag, vfrag, oacc[t], 0, 0, 0);
            }
        }
    }

#pragma unroll
    for (int r = 0; r < 4; ++r) {
        const float linv = 1.f / l_run[r];
        const int row_g = q0 + wave * 16 + quad * 4 + r;
        u16* op = attnb + (size_t)row_g * (NH * DV) + h * DV;
#pragma unroll
        for (int t = 0; t < 8; ++t)
            op[t * 16 + l16] = f2bf(oacc[t][r] * linv);
    }
}

extern "C" void kernel_launch(void* const* d_in, const int* in_sizes, int n_in,
                              void* d_out, int out_size, void* d_ws, size_t ws_size,
                              hipStream_t stream)
{
    const int*   positions = (const int*)d_in[0];
    const float* hidden    = (const float*)d_in[1];
    const float* scaling   = (const float*)d_in[2];
    const float* w_q_a     = (const float*)d_in[3];
    const float* q_a_ln_w  = (const float*)d_in[4];
    const float* w_q_b     = (const float*)d_in[5];
    const float* w_kv_a    = (const float*)d_in[6];
    const float* kv_a_ln_w = (const float*)d_in[7];
    const float* w_kv_b    = (const float*)d_in[8];
    const float* w_o       = (const float*)d_in[9];
    const float* cs_cache  = (const float*)d_in[10];
    float* out = (float*)d_out;

    char* p = (char*)d_ws;
    auto alloc = [&](size_t bytes) { char* r = p; p += (bytes + 255) & ~(size_t)255; return r; };

    // region A: hidden_bf (31.5MB) then reused as qbuf fp32 (37.7MB)
    char* regA      = alloc((size_t)T_TOK * NH * DQK * 4);
    u16*  hidden_bf = (u16*)regA;
    float* qbuf     = (float*)regA;
    // region B: q_a fp32 (18.9MB) then reused as qb bf16 (18.9MB)
    char* regB    = alloc((size_t)T_TOK * QRANK * 4);
    float* q_a    = (float*)regB;
    u16*  qb      = (u16*)regB;
    float* latent = (float*)alloc((size_t)T_TOK * (KVRANK + DR) * 4);
    u16* kpe_bf   = (u16*)alloc((size_t)T_TOK * DR * 2);
    u16* kv_bf    = (u16*)alloc((size_t)T_TOK * NH * (DN + DV) * 2);
    u16* attnb    = (u16*)alloc((size_t)T_TOK * NH * DV * 2);
    u16* q_a_bf   = (u16*)alloc((size_t)T_TOK * QRANK * 2);
    u16* kv_a_bf  = (u16*)alloc((size_t)T_TOK * KVRANK * 2);
    u16* wqa_bt   = (u16*)alloc((size_t)QRANK * HID_D * 2);
    u16* wkva_bt  = (u16*)alloc((size_t)640 * HID_D * 2);
    u16* wqb_bt   = (u16*)alloc((size_t)(NH * DQK) * QRANK * 2);
    u16* wkvb_bt  = (u16*)alloc((size_t)(NH * (DN + DV)) * KVRANK * 2);
    u16* wo_bt    = (u16*)alloc((size_t)HID_D * (NH * DV) * 2);

    const dim3 blk(256);

    // convert hidden to bf16
    convert_bf_k<<<dim3((T_TOK * HID_D / 4 + 255) / 256), blk, 0, stream>>>(
        hidden, hidden_bf, T_TOK * HID_D / 4);
    // transpose-convert weights to bf16 N x K
    transpose_conv_k<<<dim3(QRANK / 32, HID_D / 32), blk, 0, stream>>>(w_q_a, wqa_bt, HID_D, QRANK);
    transpose_conv_k<<<dim3(640 / 32, HID_D / 32), blk, 0, stream>>>(w_kv_a, wkva_bt, HID_D, KVRANK + DR);
    transpose_conv_k<<<dim3(NH * DQK / 32, QRANK / 32), blk, 0, stream>>>(w_q_b, wqb_bt, QRANK, NH * DQK);
    transpose_conv_k<<<dim3(NH * (DN + DV) / 32, KVRANK / 32), blk, 0, stream>>>(w_kv_b, wkvb_bt, KVRANK, NH * (DN + DV));
    transpose_conv_k<<<dim3(HID_D / 32, NH * DV / 32), blk, 0, stream>>>(w_o, wo_bt, NH * DV, HID_D);

    // G1: q_a = hidden @ w_q_a  (fp32 out)
    bgemm_bt_k<false><<<dim3(QRANK / 128, T_TOK / 128), blk, 0, stream>>>(
        hidden_bf, wqa_bt, q_a, QRANK, HID_D, HID_D, HID_D, QRANK);
    // G2: latent = hidden @ w_kv_a  (fp32 out, Nreal=576, Npad=640)
    bgemm_bt_k<false><<<dim3(640 / 128, T_TOK / 128), blk, 0, stream>>>(
        hidden_bf, wkva_bt, latent, KVRANK + DR, HID_D, HID_D, HID_D, KVRANK + DR);
    // k_pe rope (pre-norm latent tail)
    rope_k_conv_k<<<dim3(T_TOK), dim3(64), 0, stream>>>(latent, kpe_bf, positions, cs_cache);
    // rmsnorms -> bf16 compact
    rmsnorm_conv_k<<<dim3(T_TOK), blk, 0, stream>>>(q_a, q_a_ln_w, q_a_bf, QRANK, QRANK);
    rmsnorm_conv_k<<<dim3(T_TOK), blk, 0, stream>>>(latent, kv_a_ln_w, kv_a_bf, KVRANK, KVRANK + DR);
    // G3: q = q_a_norm @ w_q_b  (fp32 out into region A; hidden_bf dead)
    bgemm_bt_k<false><<<dim3(NH * DQK / 128, T_TOK / 128), blk, 0, stream>>>(
        q_a_bf, wqb_bt, qbuf, NH * DQK, QRANK, QRANK, QRANK, NH * DQK);
    // rope + scaling on q -> bf16 (into region B; q_a fp32 dead)
    rope_scale_q_conv_k<<<dim3(T_TOK), blk, 0, stream>>>(qbuf, positions, scaling, cs_cache, qb);
    // G4: kv = kv_a_norm @ w_kv_b  (bf16 out)
    bgemm_bt_k<true><<<dim3(NH * (DN + DV) / 128, T_TOK / 128), blk, 0, stream>>>(
        kv_a_bf, wkvb_bt, kv_bf, NH * (DN + DV), KVRANK, KVRANK, KVRANK, NH * (DN + DV));
    // flash attention (bf16 MFMA), bf16 out
    attn_mfma_k<<<dim3(T_TOK / ATT_BM, NH), blk, 0, stream>>>(qb, kv_bf, kpe_bf, attnb);
    // G5: out = attn @ w_o  (fp32 out to d_out)
    bgemm_bt_k<false><<<dim3(HID_D / 128, T_TOK / 128), blk, 0, stream>>>(
        attnb, wo_bt, out, HID_D, NH * DV, NH * DV, NH * DV, HID_D);
}

// Round 4
// 802.889 us; speedup vs baseline: 8.5672x; 1.1527x over previous
//
#include <hip/hip_runtime.h>
#include <hip/hip_bf16.h>
#include <math.h>

#define T_TOK 3072
#define HID_D 5120
#define NH 16
#define DN 128
#define DR 64
#define DQK 192
#define DV 128
#define QRANK 1536
#define KVRANK 512
#define MERGED_N 2176   // 1536 (q_a) + 640 (kv_a padded from 576)

typedef __attribute__((ext_vector_type(8))) short short8;
typedef __attribute__((ext_vector_type(4))) float f32x4;
typedef unsigned short u16;

__device__ __forceinline__ u16 f2bf(float f) {
    unsigned int u = __float_as_uint(f);
    unsigned int lsb = (u >> 16) & 1;
    u += 0x7fffu + lsb;
    return (u16)(u >> 16);
}
__device__ __forceinline__ float bf2f(u16 v) {
    return __uint_as_float(((unsigned int)v) << 16);
}

__device__ __forceinline__ void gload_lds16(const u16* g, u16* l) {
    __builtin_amdgcn_global_load_lds((const __attribute__((address_space(1))) void*)g,
                                     (__attribute__((address_space(3))) void*)l, 16, 0, 0);
}

// ---------------- fp32 -> bf16 elementwise ----------------
__global__ __launch_bounds__(256) void convert_bf_k(const float* __restrict__ x,
                                                    u16* __restrict__ y, int n4)
{
    const int i = blockIdx.x * 256 + threadIdx.x;
    if (i < n4) {
        float4 v = ((const float4*)x)[i];
        ushort4 o;
        o.x = f2bf(v.x); o.y = f2bf(v.y); o.z = f2bf(v.z); o.w = f2bf(v.w);
        ((ushort4*)y)[i] = o;
    }
}

// ---------------- fp32 K x N  ->  bf16 N x K (transposed, zero-pad cols >= N) ----------------
__global__ __launch_bounds__(256) void transpose_conv_k(const float* __restrict__ W,
                                                        u16* __restrict__ WT,
                                                        int K, int N)
{
    __shared__ float tile[32][33];
    const int n0 = blockIdx.x * 32, k0 = blockIdx.y * 32;
    const int tx = threadIdx.x & 31, ty = threadIdx.x >> 5;
#pragma unroll
    for (int i = 0; i < 32; i += 8) {
        const int nn = n0 + tx;
        tile[ty + i][tx] = (nn < N) ? W[(size_t)(k0 + ty + i) * N + nn] : 0.f;
    }
    __syncthreads();
#pragma unroll
    for (int i = 0; i < 32; i += 8) {
        WT[(size_t)(n0 + ty + i) * K + k0 + tx] = f2bf(tile[tx][ty + i]);
    }
}

// ---------------- bf16 MFMA GEMM, B transposed: C = A @ BT^T ----------------
template <bool BF16_OUT>
__global__ __launch_bounds__(256) void bgemm_bt_k(
    const u16* __restrict__ A, const u16* __restrict__ BT, void* __restrict__ C,
    int Nreal, int K, int lda, int ldb, int ldc)
{
    __shared__ __attribute__((aligned(16))) u16 As[128 * 32];
    __shared__ __attribute__((aligned(16))) u16 Bs[128 * 32];

    const int tid  = threadIdx.x;
    const int wave = tid >> 6, lane = tid & 63;
    const int quad = lane >> 4, l16 = lane & 15;
    const int wr = (wave >> 1) * 64, wc = (wave & 1) * 64;
    const int row0 = blockIdx.y * 128, col0 = blockIdx.x * 128;

    f32x4 acc[4][4];
#pragma unroll
    for (int i = 0; i < 4; ++i)
#pragma unroll
        for (int j = 0; j < 4; ++j) acc[i][j] = (f32x4){0.f, 0.f, 0.f, 0.f};

    const int sr  = tid >> 2;
    const int skc = (tid & 3) * 8;
    const u16* ap0 = A  + (size_t)(row0 + sr)      * lda + skc;
    const u16* ap1 = A  + (size_t)(row0 + sr + 64) * lda + skc;
    const u16* bp0 = BT + (size_t)(col0 + sr)      * ldb + skc;
    const u16* bp1 = BT + (size_t)(col0 + sr + 64) * ldb + skc;
    u16* al0 = As + tid * 8;
    u16* al1 = As + tid * 8 + 64 * 32;
    u16* bl0 = Bs + tid * 8;
    u16* bl1 = Bs + tid * 8 + 64 * 32;

    for (int kt = 0; kt < K; kt += 32) {
        gload_lds16(ap0 + kt, al0);
        gload_lds16(ap1 + kt, al1);
        gload_lds16(bp0 + kt, bl0);
        gload_lds16(bp1 + kt, bl1);
        __syncthreads();

        short8 af[4], bf[4];
#pragma unroll
        for (int mi = 0; mi < 4; ++mi)
            af[mi] = *(const short8*)(As + (wr + mi * 16 + l16) * 32 + quad * 8);
#pragma unroll
        for (int ni = 0; ni < 4; ++ni)
            bf[ni] = *(const short8*)(Bs + (wc + ni * 16 + l16) * 32 + quad * 8);
#pragma unroll
        for (int mi = 0; mi < 4; ++mi)
#pragma unroll
            for (int ni = 0; ni < 4; ++ni)
                acc[mi][ni] = __builtin_amdgcn_mfma_f32_16x16x32_bf16(
                    af[mi], bf[ni], acc[mi][ni], 0, 0, 0);
        __syncthreads();
    }

#pragma unroll
    for (int mi = 0; mi < 4; ++mi) {
#pragma unroll
        for (int ni = 0; ni < 4; ++ni) {
            const int col_g = col0 + wc + ni * 16 + l16;
            if (col_g < Nreal) {
#pragma unroll
                for (int r = 0; r < 4; ++r) {
                    const int row_g = row0 + wr + mi * 16 + quad * 4 + r;
                    if (BF16_OUT)
                        ((u16*)C)[(size_t)row_g * ldc + col_g] = f2bf(acc[mi][ni][r]);
                    else
                        ((float*)C)[(size_t)row_g * ldc + col_g] = acc[mi][ni][r];
                }
            }
        }
    }
}

// ---------------- RMSNorm: bf16 strided in -> bf16 compact out ----------------
__global__ __launch_bounds__(256) void rmsnorm_bf_k(const u16* __restrict__ x,
                                                    const float* __restrict__ w,
                                                    u16* __restrict__ y,
                                                    int width, int stride, int off)
{
    const int row = blockIdx.x;
    const u16* xr = x + (size_t)row * stride + off;
    float ss = 0.f;
    for (int i = threadIdx.x; i < width; i += 256) {
        float v = bf2f(xr[i]);
        ss += v * v;
    }
    __shared__ float red[256];
    red[threadIdx.x] = ss;
    __syncthreads();
    for (int s = 128; s > 0; s >>= 1) {
        if (threadIdx.x < s) red[threadIdx.x] += red[threadIdx.x + s];
        __syncthreads();
    }
    const float scale = rsqrtf(red[0] / (float)width + 1e-6f);
    for (int i = threadIdx.x; i < width; i += 256)
        y[(size_t)row * width + i] = f2bf(bf2f(xr[i]) * scale * w[i]);
}

// ---------------- RoPE on q (bf16 in) + llama_4 scaling -> bf16 out ----------------
__global__ void rope_scale_q_bf_k(const u16* __restrict__ q, const int* __restrict__ positions,
                                  const float* __restrict__ scaling,
                                  const float* __restrict__ cs_cache, u16* __restrict__ qb)
{
    const int t = blockIdx.x;
    const int pos = positions[t];
    const float* cs = cs_cache + (size_t)pos * DR;
    const float s = scaling[t];
    __shared__ float c_sh[32], s_sh[32];
    if (threadIdx.x < 32) {
        c_sh[threadIdx.x] = cs[threadIdx.x];
        s_sh[threadIdx.x] = cs[32 + threadIdx.x];
    }
    __syncthreads();
    const int tid = threadIdx.x;
    for (int h = 0; h < NH; ++h) {
        const u16* qr = q + ((size_t)t * NH + h) * DQK;
        u16* qo = qb + ((size_t)t * NH + h) * DQK;
        if (tid < 128) {
            qo[tid] = f2bf(bf2f(qr[tid]) * s);
        } else if (tid < 160) {
            const int d = tid - 128;
            const float x1 = bf2f(qr[128 + d]), x2 = bf2f(qr[160 + d]);
            qo[128 + d] = f2bf((x1 * c_sh[d] - x2 * s_sh[d]) * s);
            qo[160 + d] = f2bf((x2 * c_sh[d] + x1 * s_sh[d]) * s);
        }
    }
}

// ---------------- RoPE on k_pe (pre-norm merged-latent tail, bf16) -> bf16 ----------------
__global__ void rope_k_bf_k(const u16* __restrict__ qa_lat, u16* __restrict__ kpe,
                            const int* __restrict__ positions,
                            const float* __restrict__ cs_cache)
{
    const int t = blockIdx.x;
    const int d = threadIdx.x;
    if (d >= 32) return;
    const int pos = positions[t];
    const float* cs = cs_cache + (size_t)pos * DR;
    const float c = cs[d], sn = cs[32 + d];
    const u16* lr = qa_lat + (size_t)t * MERGED_N + QRANK + KVRANK;
    const float x1 = bf2f(lr[d]), x2 = bf2f(lr[32 + d]);
    kpe[(size_t)t * DR + d]      = f2bf(x1 * c - x2 * sn);
    kpe[(size_t)t * DR + 32 + d] = f2bf(x2 * c + x1 * sn);
}

// ---------------- transpose V: kv_bf (T,NH,256)[...,128:] -> vt (NH,DV,T) ----------------
__global__ __launch_bounds__(256) void transpose_v_k(const u16* __restrict__ kvb,
                                                     u16* __restrict__ vt)
{
    __shared__ u16 tile[64][72];
    const int t0 = blockIdx.x * 64, d0 = blockIdx.y * 64, h = blockIdx.z;
    const int tid = threadIdx.x;
    for (int cc = tid; cc < 64 * 8; cc += 256) {
        const int row = cc >> 3, c = (cc & 7) * 8;   // row=t, c=dv
        *(short8*)&tile[row][c] =
            *(const short8*)(kvb + ((size_t)(t0 + row) * NH + h) * (DN + DV) + DN + d0 + c);
    }
    __syncthreads();
    for (int cc = tid; cc < 64 * 8; cc += 256) {
        const int drow = cc >> 3, c = (cc & 7) * 8;  // drow=dv, c=t
        short8 s;
#pragma unroll
        for (int j = 0; j < 8; ++j) s[j] = tile[c + j][drow];
        *(short8*)(vt + ((size_t)h * DV + d0 + drow) * T_TOK + t0 + c) = s;
    }
}

// ---------------- bf16 MFMA flash attention v2 ----------------
// 512 thr = 8 waves, BM=128 (16 rows/wave), BN=64.
// qb (T,NH,192), kvb (T,NH,256)=[k_nope|v], kpeb (T,64), vt (NH,DV,T), out attnb bf16.
#define ATT_BM 128
#define ATT_BN 64
__global__ __launch_bounds__(512) void attn_mfma_k(
    const u16* __restrict__ qb, const u16* __restrict__ kvb,
    const u16* __restrict__ kpeb, const u16* __restrict__ vt,
    u16* __restrict__ attnb)
{
    __shared__ u16 Ks[ATT_BN][200];   // 64 keys x 192, +8 pad
    __shared__ u16 Vt[DV][72];        // [dv][key], +8 pad
    __shared__ u16 Ps[8][16][72];     // per-wave P

    const int tid  = threadIdx.x;
    const int wave = tid >> 6;
    const int lane = tid & 63;
    const int quad = lane >> 4;
    const int l16  = lane & 15;

    const int qblk = (int)gridDim.x - 1 - (int)blockIdx.x;  // heavy blocks first
    const int h    = blockIdx.y;
    const int q0   = qblk * ATT_BM;
    const int wrow0 = q0 + wave * 16;          // wave's first q row
    const int qrow  = wrow0 + l16;

    short8 qf[6];
    {
        const u16* qp = qb + ((size_t)qrow * NH + h) * DQK + quad * 8;
#pragma unroll
        for (int c = 0; c < 6; ++c)
            qf[c] = *(const short8*)(qp + c * 32);
    }

    f32x4 oacc[8];
#pragma unroll
    for (int t = 0; t < 8; ++t) oacc[t] = (f32x4){0.f, 0.f, 0.f, 0.f};
    float m_old[4], l_run[4];
#pragma unroll
    for (int r = 0; r < 4; ++r) { m_old[r] = -1e30f; l_run[r] = 0.f; }

    const int nkt = (q0 + ATT_BM) / ATT_BN;
    for (int kt = 0; kt < nkt; ++kt) {
        const int k0 = kt * ATT_BN;
        __syncthreads();   // previous tile's Ks/Vt reads done
        // stage K tile: 64 rows x 24 chunks of 8 -> 1536 chunks / 512 thr = 3
        for (int cc = tid; cc < 64 * 24; cc += 512) {
            const int row = cc / 24, c = cc % 24;
            short8 v;
            if (c < 16) v = *(const short8*)(kvb + ((size_t)(k0 + row) * NH + h) * (DN + DV) + c * 8);
            else        v = *(const short8*)(kpeb + (size_t)(k0 + row) * DR + (c - 16) * 8);
            *(short8*)&Ks[row][c * 8] = v;
        }
        // stage V^T tile: 128 dv-rows x 8 chunks -> 1024 / 512 = 2
        for (int cc = tid; cc < DV * 8; cc += 512) {
            const int row = cc >> 3, c = (cc & 7) * 8;
            *(short8*)&Vt[row][c] =
                *(const short8*)(vt + ((size_t)h * DV + row) * T_TOK + k0 + c);
        }
        __syncthreads();

        if (k0 <= wrow0 + 15) {   // wave has at least one unmasked row
            f32x4 sacc[4];
#pragma unroll
            for (int t = 0; t < 4; ++t) sacc[t] = (f32x4){0.f, 0.f, 0.f, 0.f};
#pragma unroll
            for (int t = 0; t < 4; ++t) {
                const u16* kp = &Ks[t * 16 + l16][quad * 8];
#pragma unroll
                for (int c = 0; c < 6; ++c) {
                    short8 bfrag = *(const short8*)(kp + c * 32);
                    sacc[t] = __builtin_amdgcn_mfma_f32_16x16x32_bf16(qf[c], bfrag, sacc[t], 0, 0, 0);
                }
            }
            const float sc = 0.07216878364870322f;   // 1/sqrt(192)
            const int rbase = wrow0 + quad * 4;
            if (k0 + ATT_BN - 1 > wrow0) {
                // diagonal-ish tile: mask
#pragma unroll
                for (int t = 0; t < 4; ++t) {
                    const int colg = k0 + t * 16 + l16;
#pragma unroll
                    for (int r = 0; r < 4; ++r) {
                        const float s = sacc[t][r] * sc;
                        sacc[t][r] = (rbase + r >= colg) ? s : -1e30f;
                    }
                }
            } else {
#pragma unroll
                for (int t = 0; t < 4; ++t)
#pragma unroll
                    for (int r = 0; r < 4; ++r) sacc[t][r] *= sc;
            }
            float alpha[4];
#pragma unroll
            for (int r = 0; r < 4; ++r) {
                float mx = fmaxf(fmaxf(sacc[0][r], sacc[1][r]), fmaxf(sacc[2][r], sacc[3][r]));
                mx = fmaxf(mx, __shfl_xor(mx, 1));
                mx = fmaxf(mx, __shfl_xor(mx, 2));
                mx = fmaxf(mx, __shfl_xor(mx, 4));
                mx = fmaxf(mx, __shfl_xor(mx, 8));
                const float mnew = fmaxf(m_old[r], mx);
                alpha[r] = __expf(m_old[r] - mnew);
                float sum = 0.f;
#pragma unroll
                for (int t = 0; t < 4; ++t) {
                    const float p = __expf(sacc[t][r] - mnew);
                    sacc[t][r] = p;
                    sum += p;
                }
                sum += __shfl_xor(sum, 1);
                sum += __shfl_xor(sum, 2);
                sum += __shfl_xor(sum, 4);
                sum += __shfl_xor(sum, 8);
                l_run[r] = l_run[r] * alpha[r] + sum;
                m_old[r] = mnew;
            }
            // P (C-layout) -> per-wave LDS as bf16 (A-layout source for PV)
#pragma unroll
            for (int t = 0; t < 4; ++t)
#pragma unroll
                for (int r = 0; r < 4; ++r)
                    Ps[wave][quad * 4 + r][t * 16 + l16] = f2bf(sacc[t][r]);
#pragma unroll
            for (int t = 0; t < 8; ++t)
#pragma unroll
                for (int r = 0; r < 4; ++r)
                    oacc[t][r] *= alpha[r];
            // same-wave LDS write->read: compiler-inserted lgkmcnt, no barrier needed
#pragma unroll
            for (int ch = 0; ch < 2; ++ch) {
                short8 pfrag = *(const short8*)&Ps[wave][l16][ch * 32 + quad * 8];
#pragma unroll
                for (int t = 0; t < 8; ++t) {
                    short8 vfrag = *(const short8*)&Vt[t * 16 + l16][ch * 32 + quad * 8];
                    oacc[t] = __builtin_amdgcn_mfma_f32_16x16x32_bf16(pfrag, vfrag, oacc[t], 0, 0, 0);
                }
            }
        }
    }

#pragma unroll
    for (int r = 0; r < 4; ++r) {
        const float linv = 1.f / l_run[r];
        const int row_g = wrow0 + quad * 4 + r;
        u16* op = attnb + (size_t)row_g * (NH * DV) + h * DV;
#pragma unroll
        for (int t = 0; t < 8; ++t)
            op[t * 16 + l16] = f2bf(oacc[t][r] * linv);
    }
}

extern "C" void kernel_launch(void* const* d_in, const int* in_sizes, int n_in,
                              void* d_out, int out_size, void* d_ws, size_t ws_size,
                              hipStream_t stream)
{
    const int*   positions = (const int*)d_in[0];
    const float* hidden    = (const float*)d_in[1];
    const float* scaling   = (const float*)d_in[2];
    const float* w_q_a     = (const float*)d_in[3];
    const float* q_a_ln_w  = (const float*)d_in[4];
    const float* w_q_b     = (const float*)d_in[5];
    const float* w_kv_a    = (const float*)d_in[6];
    const float* kv_a_ln_w = (const float*)d_in[7];
    const float* w_kv_b    = (const float*)d_in[8];
    const float* w_o       = (const float*)d_in[9];
    const float* cs_cache  = (const float*)d_in[10];
    float* out = (float*)d_out;

    char* p = (char*)d_ws;
    auto alloc = [&](size_t bytes) { char* r = p; p += (bytes + 255) & ~(size_t)255; return r; };

    // region H: hidden_bf (31.5MB), later reused as qraw_bf (18.9MB)
    char* regH      = alloc((size_t)T_TOK * HID_D * 2);
    u16*  hidden_bf = (u16*)regH;
    u16*  qraw_bf   = (u16*)regH;
    // region Q: qa_lat (13.4MB) + q_a_norm (9.4MB); later reused as qb (18.9MB)
    char* regQ      = alloc((size_t)T_TOK * MERGED_N * 2 + (size_t)T_TOK * QRANK * 2);
    u16*  qa_lat    = (u16*)regQ;
    u16*  q_a_norm  = (u16*)(regQ + (size_t)T_TOK * MERGED_N * 2);
    u16*  qb        = (u16*)regQ;
    u16* kv_a_norm = (u16*)alloc((size_t)T_TOK * KVRANK * 2);
    u16* kpe_bf    = (u16*)alloc((size_t)T_TOK * DR * 2);
    u16* kv_bf     = (u16*)alloc((size_t)T_TOK * NH * (DN + DV) * 2);
    u16* vt        = (u16*)alloc((size_t)NH * DV * T_TOK * 2);
    u16* attnb     = (u16*)alloc((size_t)T_TOK * NH * DV * 2);
    u16* wqakva_bt = (u16*)alloc((size_t)MERGED_N * HID_D * 2);
    u16* wqb_bt    = (u16*)alloc((size_t)(NH * DQK) * QRANK * 2);
    u16* wkvb_bt   = (u16*)alloc((size_t)(NH * (DN + DV)) * KVRANK * 2);
    u16* wo_bt     = (u16*)alloc((size_t)HID_D * (NH * DV) * 2);

    const dim3 blk(256);

    convert_bf_k<<<dim3((T_TOK * HID_D / 4 + 255) / 256), blk, 0, stream>>>(
        hidden, hidden_bf, T_TOK * HID_D / 4);
    // merged weight transpose: rows [0,1536) = w_q_a^T, rows [1536,2176) = w_kv_a^T (zero-padded)
    transpose_conv_k<<<dim3(QRANK / 32, HID_D / 32), blk, 0, stream>>>(
        w_q_a, wqakva_bt, HID_D, QRANK);
    transpose_conv_k<<<dim3(640 / 32, HID_D / 32), blk, 0, stream>>>(
        w_kv_a, wqakva_bt + (size_t)QRANK * HID_D, HID_D, KVRANK + DR);
    transpose_conv_k<<<dim3(NH * DQK / 32, QRANK / 32), blk, 0, stream>>>(w_q_b, wqb_bt, QRANK, NH * DQK);
    transpose_conv_k<<<dim3(NH * (DN + DV) / 32, KVRANK / 32), blk, 0, stream>>>(w_kv_b, wkvb_bt, KVRANK, NH * (DN + DV));
    transpose_conv_k<<<dim3(HID_D / 32, NH * DV / 32), blk, 0, stream>>>(w_o, wo_bt, NH * DV, HID_D);

    // merged G1+G2: qa_lat = hidden @ [w_q_a | w_kv_a]  (bf16 out, Nreal=2112)
    bgemm_bt_k<true><<<dim3(MERGED_N / 128, T_TOK / 128), blk, 0, stream>>>(
        hidden_bf, wqakva_bt, qa_lat, QRANK + KVRANK + DR, HID_D, HID_D, HID_D, MERGED_N);
    // k_pe rope from pre-norm latent tail (cols 2048..2111 of qa_lat)
    rope_k_bf_k<<<dim3(T_TOK), dim3(64), 0, stream>>>(qa_lat, kpe_bf, positions, cs_cache);
    // rmsnorms -> compact bf16
    rmsnorm_bf_k<<<dim3(T_TOK), blk, 0, stream>>>(qa_lat, q_a_ln_w, q_a_norm, QRANK, MERGED_N, 0);
    rmsnorm_bf_k<<<dim3(T_TOK), blk, 0, stream>>>(qa_lat, kv_a_ln_w, kv_a_norm, KVRANK, MERGED_N, QRANK);
    // G3: qraw = q_a_norm @ w_q_b  (bf16 out, into region H)
    bgemm_bt_k<true><<<dim3(NH * DQK / 128, T_TOK / 128), blk, 0, stream>>>(
        q_a_norm, wqb_bt, qraw_bf, NH * DQK, QRANK, QRANK, QRANK, NH * DQK);
    // rope + scaling on q -> qb (region Q; qa_lat/q_a_norm dead)
    rope_scale_q_bf_k<<<dim3(T_TOK), blk, 0, stream>>>(qraw_bf, positions, scaling, cs_cache, qb);
    // G4: kv = kv_a_norm @ w_kv_b  (bf16 out)
    bgemm_bt_k<true><<<dim3(NH * (DN + DV) / 128, T_TOK / 128), blk, 0, stream>>>(
        kv_a_norm, wkvb_bt, kv_bf, NH * (DN + DV), KVRANK, KVRANK, KVRANK, NH * (DN + DV));
    // global V transpose: vt[h][dv][t]
    transpose_v_k<<<dim3(T_TOK / 64, DV / 64, NH), blk, 0, stream>>>(kv_bf, vt);
    // flash attention v2
    attn_mfma_k<<<dim3(T_TOK / ATT_BM, NH), dim3(512), 0, stream>>>(qb, kv_bf, kpe_bf, vt, attnb);
    // G5: out = attn @ w_o  (fp32 out)
    bgemm_bt_k<false><<<dim3(HID_D / 128, T_TOK / 128), blk, 0, stream>>>(
        attnb, wo_bt, out, HID_D, NH * DV, NH * DV, NH * DV, HID_D);
}